// Round 33
// baseline (318.552 us; speedup 1.0000x reference)
//
#include <hip/hip_runtime.h>
#include <math.h>

#define BB 2
#define SEQ 4096
#define DMODEL 768
#define DSTATE 128
#define NHH 24
#define HDIM 64
#define DSSM 1536
#define CDIM 1792
#define CHK 256
#define NC 16
#define DPROJ 3352
#define MR (BB*SEQ)
#define KSPLIT 32
#define XSTR 1920
#define CT 16
#define SXS 270
#define STS 134

typedef __attribute__((ext_vector_type(8))) short bf16x8;
typedef __attribute__((ext_vector_type(8))) unsigned short u16x8;
typedef __attribute__((ext_vector_type(4))) float f32x4;

__device__ __forceinline__ float siluf(float x) { return x / (1.0f + expf(-x)); }

__device__ __forceinline__ unsigned short f2bf(float f) {
    unsigned u = __float_as_uint(f);
    unsigned r = (u + 0x7fffu + ((u >> 16) & 1u)) >> 16;
    return (unsigned short)r;
}

__device__ __forceinline__ float bf2f(unsigned short u) {
    return __uint_as_float(((unsigned)u) << 16);
}

__device__ __forceinline__ float4 bf2f4(ushort4 v) {
    float4 o;
    o.x = bf2f(v.x); o.y = bf2f(v.y); o.z = bf2f(v.z); o.w = bf2f(v.w);
    return o;
}

__device__ __forceinline__ bf16x8 pack8(float4 a, float4 b) {
    u16x8 r;
    r[0] = f2bf(a.x); r[1] = f2bf(a.y); r[2] = f2bf(a.z); r[3] = f2bf(a.w);
    r[4] = f2bf(b.x); r[5] = f2bf(b.y); r[6] = f2bf(b.z); r[7] = f2bf(b.w);
    return *(bf16x8*)&r;
}

__device__ __forceinline__ void gload_lds16(const void* g, void* l) {
    __builtin_amdgcn_global_load_lds((const __attribute__((address_space(1))) unsigned int*)g,
                                     (__attribute__((address_space(3))) unsigned int*)l, 16, 0, 0);
}

// ---------------- f32 -> bf16 conversion, 3 tensors in one launch.
// Tensor 2 (W_out) is multiplied by norm_w[k] (RMSNorm weight folding).
__global__ __launch_bounds__(256) void cvt3_k(
    const float* __restrict__ in0, unsigned short* __restrict__ out0, int nb0, int nv0,
    const float* __restrict__ in1, unsigned short* __restrict__ out1, int nb1, int nv1,
    const float* __restrict__ in2, unsigned short* __restrict__ out2, int nb2, int nv2,
    const float* __restrict__ nwv)
{
    int b = blockIdx.x;
    const float* in; unsigned short* out; int nvalid; int base; int which;
    if (b < nb0) { in = in0; out = out0; nvalid = nv0; base = b; which = 0; }
    else if (b < nb0 + nb1) { in = in1; out = out1; nvalid = nv1; base = b - nb0; which = 1; }
    else { in = in2; out = out2; nvalid = nv2; base = b - nb0 - nb1; which = 2; }
    int i = (base * 256 + threadIdx.x) * 4;
    ushort4 o;
    if (i + 3 < nvalid) {
        float4 v = *(const float4*)&in[i];
        if (which == 2) {
            int k = i % DSSM;                    // i multiple of 4, DSSM%4==0
            float4 s4 = *(const float4*)&nwv[k];
            v.x *= s4.x; v.y *= s4.y; v.z *= s4.z; v.w *= s4.w;
        }
        o.x = f2bf(v.x); o.y = f2bf(v.y); o.z = f2bf(v.z); o.w = f2bf(v.w);
    } else {
        o.x = (i + 0 < nvalid) ? f2bf(in[i + 0]) : 0;
        o.y = (i + 1 < nvalid) ? f2bf(in[i + 1]) : 0;
        o.z = (i + 2 < nvalid) ? f2bf(in[i + 2]) : 0;
        o.w = (i + 3 < nvalid) ? f2bf(in[i + 3]) : 0;
    }
    *(ushort4*)&out[i] = o;
}

// ---------------- MEGA1: DUAL bf16 GEMM 128x128 (tri-buffered, swizzled) + skinny1 MFMA
__global__ __launch_bounds__(256) void gemm_dual_skinny(
    const unsigned short* __restrict__ A,
    const unsigned short* __restrict__ B1, const float* __restrict__ bias1,
    unsigned short* __restrict__ C1, int N1, int NT1, int nbias1, int NWG1,
    const unsigned short* __restrict__ B2, const float* __restrict__ bias2,
    unsigned short* __restrict__ C2, int N2, int NT2, int nbias2,
    int K, int KT, int NWGD,
    const float* __restrict__ skA, const float* __restrict__ skB,
    float* __restrict__ skPart, int skN, int skK)
{
    __shared__ unsigned short SMEM[24576];   // 3 bufs x 8192 ushorts = 48KB
    const int tid = threadIdx.x;
    const int w = tid >> 6, l = tid & 63;
    const int lr = l & 15, lk = l >> 4;
    int nwg = gridDim.x, bid = blockIdx.x;
    int wg = (nwg & 7) ? bid : ((bid & 7) * (nwg >> 3) + (bid >> 3));
    if (wg >= NWGD) {
        // ---- skinny1 path: M=48 split-K(32) MFMA, LDS-free ----
        int t = wg - NWGD;
        int nb = t & 31, kb = t >> 5;
        const int n0s = nb * 128;
        const int KS = skK / KSPLIT;          // 128
        const int k0 = kb * KS;
        const int nw0 = n0s + w * 32;
        f32x4 sacc[3][2] = {};
        for (int kt = 0; kt < KS; kt += 32) {
            int kk = k0 + kt + lk * 8;
            bf16x8 af[3], bfr[2];
#pragma unroll
            for (int mi = 0; mi < 3; ++mi) {
                const float* ap = &skA[(size_t)(mi * 16 + lr) * skK + kk];
                af[mi] = pack8(*(const float4*)ap, *(const float4*)(ap + 4));
            }
#pragma unroll
            for (int nf = 0; nf < 2; ++nf) {
                const float* bp = &skB[(size_t)(nw0 + nf * 16 + lr) * skK + kk];
                bfr[nf] = pack8(*(const float4*)bp, *(const float4*)(bp + 4));
            }
#pragma unroll
            for (int mi = 0; mi < 3; ++mi)
#pragma unroll
                for (int nf = 0; nf < 2; ++nf)
                    sacc[mi][nf] = __builtin_amdgcn_mfma_f32_16x16x32_bf16(af[mi], bfr[nf], sacc[mi][nf], 0, 0, 0);
        }
        float* pb = skPart + (size_t)kb * 48 * skN;
#pragma unroll
        for (int mi = 0; mi < 3; ++mi)
#pragma unroll
            for (int r = 0; r < 4; ++r)
#pragma unroll
                for (int nf = 0; nf < 2; ++nf)
                    pb[(size_t)(mi * 16 + lk * 4 + r) * skN + nw0 + nf * 16 + lr] = sacc[mi][nf][r];
        return;
    }
    // ---- dual GEMM path ----
    const int wr = w >> 1, wc = w & 1;
    const int lkx = lk ^ ((lr >> 1) & 3);
    const unsigned short* B;
    const float* bias;
    unsigned short* C;
    int N, NT, nbias;
    if (wg < NWG1) { B = B1; bias = bias1; C = C1; N = N1; NT = NT1; nbias = nbias1; }
    else { wg -= NWG1; B = B2; bias = bias2; C = C2; N = N2; NT = NT2; nbias = nbias2; }
    const int m0 = (wg / NT) * 128, n0 = (wg % NT) * 128;
    f32x4 acc[4][4] = {};
    const int i16 = w * 64 + l;
    const int row0 = i16 >> 2, sl = i16 & 3;
    const int slx = sl ^ ((row0 >> 1) & 3);
    const size_t ga0 = (size_t)(m0 + row0) * K + slx * 8;
    const size_t ga1 = (size_t)(m0 + row0 + 64) * K + slx * 8;
    const size_t gb0 = (size_t)(n0 + row0) * K + slx * 8;
    const size_t gb1 = (size_t)(n0 + row0 + 64) * K + slx * 8;
    const int lo0 = (w * 64) * 8;
    const int lo1 = (256 + w * 64) * 8;

#define STAGE(bb, kt) { int ko = (kt) * 32; int bs = (bb) * 8192;            \
      gload_lds16(A + ga0 + ko, &SMEM[bs + lo0]);                            \
      gload_lds16(A + ga1 + ko, &SMEM[bs + lo1]);                            \
      gload_lds16(B + gb0 + ko, &SMEM[bs + 4096 + lo0]);                     \
      gload_lds16(B + gb1 + ko, &SMEM[bs + 4096 + lo1]); }

    STAGE(0, 0);
    STAGE(1, 1);
    for (int kt = 0; kt < KT; ++kt) {
        if (kt + 1 < KT) {
            asm volatile("s_waitcnt vmcnt(4)" ::: "memory");
        } else {
            asm volatile("s_waitcnt vmcnt(0)" ::: "memory");
        }
        __builtin_amdgcn_s_barrier();
        if (kt + 2 < KT) STAGE((kt + 2) % 3, kt + 2);
        int bs = (kt % 3) * 8192;
        bf16x8 af[4], bg[4];
#pragma unroll
        for (int mi = 0; mi < 4; ++mi)
            af[mi] = *(const bf16x8*)&SMEM[bs + (wr * 64 + mi * 16 + lr) * 32 + lkx * 8];
#pragma unroll
        for (int nj = 0; nj < 4; ++nj)
            bg[nj] = *(const bf16x8*)&SMEM[bs + 4096 + (wc * 64 + nj * 16 + lr) * 32 + lkx * 8];
#pragma unroll
        for (int mi = 0; mi < 4; ++mi)
#pragma unroll
            for (int nj = 0; nj < 4; ++nj)
                acc[mi][nj] = __builtin_amdgcn_mfma_f32_16x16x32_bf16(af[mi], bg[nj], acc[mi][nj], 0, 0, 0);
    }
#undef STAGE
    {
        unsigned short* CL = SMEM;
#pragma unroll
        for (int half = 0; half < 2; ++half) {
            __syncthreads();
            if (wr == half) {
#pragma unroll
                for (int nj = 0; nj < 4; ++nj) {
                    int col = n0 + wc * 64 + nj * 16 + lr;
                    float bz = (col < nbias) ? bias[col] : 0.f;
                    int cl = wc * 64 + nj * 16 + lr;
#pragma unroll
                    for (int mi = 0; mi < 4; ++mi)
#pragma unroll
                        for (int r = 0; r < 4; ++r)
                            CL[(mi * 16 + lk * 4 + r) * 136 + cl] = f2bf(acc[mi][nj][r] + bz);
                }
            }
            __syncthreads();
            for (int i = tid; i < 1024; i += 256) {
                int rr = i >> 4, c8 = (i & 15) * 8;
                int m = m0 + half * 64 + rr;
                *(u16x8*)&C[(size_t)m * N + n0 + c8] = *(const u16x8*)&CL[rr * 136 + c8];
            }
        }
    }
}

// ---------------- MEGA2: conv (blocks 0..895) + skinny2 MFMA (896..1919)
__global__ __launch_bounds__(256) void conv_skinny2_k(const unsigned short* __restrict__ xbc,
    const float* __restrict__ cw, const float* __restrict__ cb,
    unsigned short* __restrict__ out,
    const float* __restrict__ skA, const float* __restrict__ skB,
    float* __restrict__ skPart, int skN, int skK, int NWGC)
{
    int bid = blockIdx.x;
    int tid = threadIdx.x;
    if (bid >= NWGC) {
        int t = bid - NWGC;
        int nb = t & 31, kb = t >> 5;
        const int n0s = nb * 128;
        const int KS = skK / KSPLIT;
        const int k0 = kb * KS;
        const int w = tid >> 6, l = tid & 63;
        const int lr = l & 15, lk = l >> 4;
        const int nw0 = n0s + w * 32;
        f32x4 sacc[3][2] = {};
        for (int kt = 0; kt < KS; kt += 32) {
            int kk = k0 + kt + lk * 8;
            bf16x8 af[3], bfr[2];
#pragma unroll
            for (int mi = 0; mi < 3; ++mi) {
                const float* ap = &skA[(size_t)(mi * 16 + lr) * skK + kk];
                af[mi] = pack8(*(const float4*)ap, *(const float4*)(ap + 4));
            }
#pragma unroll
            for (int nf = 0; nf < 2; ++nf) {
                const float* bp = &skB[(size_t)(nw0 + nf * 16 + lr) * skK + kk];
                bfr[nf] = pack8(*(const float4*)bp, *(const float4*)(bp + 4));
            }
#pragma unroll
            for (int mi = 0; mi < 3; ++mi)
#pragma unroll
                for (int nf = 0; nf < 2; ++nf)
                    sacc[mi][nf] = __builtin_amdgcn_mfma_f32_16x16x32_bf16(af[mi], bfr[nf], sacc[mi][nf], 0, 0, 0);
        }
        float* pb = skPart + (size_t)kb * 48 * skN;
#pragma unroll
        for (int mi = 0; mi < 3; ++mi)
#pragma unroll
            for (int r = 0; r < 4; ++r)
#pragma unroll
                for (int nf = 0; nf < 2; ++nf)
                    pb[(size_t)(mi * 16 + lk * 4 + r) * skN + nw0 + nf * 16 + lr] = sacc[mi][nf][r];
        return;
    }
    // ---- conv path ----
    int idx = bid * 256 + tid;
    int slot = idx % 448;
    int g = idx / 448;
    int c4 = slot * 4;
    int b = g / (SEQ / CT);
    int t0 = (g % (SEQ / CT)) * CT;
    size_t rb = (size_t)b * SEQ;
    float4 cw0 = *(const float4*)&cw[(c4 + 0) * 4];
    float4 cw1 = *(const float4*)&cw[(c4 + 1) * 4];
    float4 cw2 = *(const float4*)&cw[(c4 + 2) * 4];
    float4 cw3 = *(const float4*)&cw[(c4 + 3) * 4];
    float4 cbv = *(const float4*)&cb[c4];
    float4 zero = {0.f, 0.f, 0.f, 0.f};
    float4 w0, w1, w2;
    w0 = (t0 - 3 >= 0) ? bf2f4(*(const ushort4*)&xbc[(rb + t0 - 3) * XSTR + c4]) : zero;
    w1 = (t0 - 2 >= 0) ? bf2f4(*(const ushort4*)&xbc[(rb + t0 - 2) * XSTR + c4]) : zero;
    w2 = (t0 - 1 >= 0) ? bf2f4(*(const ushort4*)&xbc[(rb + t0 - 1) * XSTR + c4]) : zero;
#pragma unroll
    for (int i = 0; i < CT; ++i) {
        int t = t0 + i;
        float4 w3 = bf2f4(*(const ushort4*)&xbc[(rb + t) * XSTR + c4]);
        float a0 = cbv.x + w0.x * cw0.x + w1.x * cw0.y + w2.x * cw0.z + w3.x * cw0.w;
        float a1 = cbv.y + w0.y * cw1.x + w1.y * cw1.y + w2.y * cw1.z + w3.y * cw1.w;
        float a2 = cbv.z + w0.z * cw2.x + w1.z * cw2.y + w2.z * cw2.z + w3.z * cw2.w;
        float a3 = cbv.w + w0.w * cw3.x + w1.w * cw3.y + w2.w * cw3.z + w3.w * cw3.w;
        ushort4 o;
        o.x = f2bf(siluf(a0)); o.y = f2bf(siluf(a1));
        o.z = f2bf(siluf(a2)); o.w = f2bf(siluf(a3));
        *(ushort4*)&out[(rb + t) * CDIM + c4] = o;
        w0 = w1; w1 = w2; w2 = w3;
    }
}

// ---------------- reduce split-K partials + bias (+ optional silu)
__global__ __launch_bounds__(256) void reduce_part_k(const float* __restrict__ part,
    const float* __restrict__ bias, float* __restrict__ out, int N, int act)
{
    int idx = blockIdx.x * 256 + threadIdx.x;
    if (idx >= 48 * N) return;
    int n = idx % N;
    float s = bias[n];
#pragma unroll
    for (int kb = 0; kb < KSPLIT; ++kb) s += part[(size_t)kb * 48 * N + idx];
    if (act) s = siluf(s);
    out[idx] = s;
}

// ---------------- per-(b,h) row, chunked over SEQ (4 chunks x 1024, halo 6):
// tdt0 = ts*td; conv1+silu; conv2+silu  (FIR convs -> chunking exact)
__global__ __launch_bounds__(256) void time_conv_k(const float* __restrict__ ts,
    const float* __restrict__ td, const float* __restrict__ w1, const float* __restrict__ b1,
    const float* __restrict__ w2, const float* __restrict__ b2, float* __restrict__ tdt)
{
    __shared__ float u0[1030];
    __shared__ float u1[1027];
    int row = blockIdx.x >> 2;
    int cq = blockIdx.x & 3;
    int h = row % NHH;
    int t0 = cq * 1024;
    const float* tsr = ts + (size_t)row * SEQ;
    const float* tdr = td + (size_t)row * SEQ;
    for (int j = threadIdx.x; j < 1030; j += 256) {
        int t = t0 - 6 + j;
        u0[j] = (t >= 0 && t < SEQ) ? tsr[t] * tdr[t] : 0.f;
    }
    __syncthreads();
    float wa[4], wb[4];
#pragma unroll
    for (int k = 0; k < 4; ++k) { wa[k] = w1[h * 4 + k]; wb[k] = w2[h * 4 + k]; }
    float ba = b1[h], bbv = b2[h];
    for (int j = threadIdx.x; j < 1027; j += 256) {
        int t = t0 - 3 + j;
        float acc = ba;
#pragma unroll
        for (int k = 0; k < 4; ++k) acc = fmaf(u0[j + k], wa[k], acc);   // u0 zero-padded
        u1[j] = (t >= 0) ? siluf(acc) : 0.f;                             // conv2 input pad=0
    }
    __syncthreads();
    for (int j = threadIdx.x; j < 1024; j += 256) {
        int t = t0 + j;
        float acc = bbv;
#pragma unroll
        for (int k = 0; k < 4; ++k) acc = fmaf(u1[j + k], wb[k], acc);
        tdt[(size_t)row * SEQ + t] = siluf(acc);
    }
}

// ---------------- fused: dt_sp softplus + per-chunk cumsum acs; zeroes ss buffer
__global__ __launch_bounds__(256) void dtsp_cum_k(const unsigned short* __restrict__ r1,
    const float* __restrict__ tdt, const float* __restrict__ dt_bias,
    const float* __restrict__ A_log, float* __restrict__ dtp, float* __restrict__ acs,
    float* __restrict__ ssb)
{
    __shared__ float wsum[4];
    int blk = blockIdx.x;
    int tid = threadIdx.x;
    if (blk < 32) ssb[blk * 256 + tid] = 0.f;   // zero MR floats for y2's row-SS atomics
    int c = blk % NC;
    int bh = blk / NC;
    int h = bh % NHH, b = bh / NHH;
    int s = c * CHK + tid;
    size_t base = (size_t)bh * SEQ + s;
    float x = bf2f(r1[((size_t)(b * SEQ + s)) * XSTR + CDIM + h]) * tdt[base] + dt_bias[h];
    float dt = (x > 20.0f) ? x : log1pf(expf(x));
    dtp[base] = dt;
    float Ah = -expf(A_log[h]);
    float v = Ah * dt;
    int ln = tid & 63;
#pragma unroll
    for (int off = 1; off < 64; off <<= 1) {
        float t = __shfl_up(v, off, 64);
        if (ln >= off) v += t;
    }
    if (ln == 63) wsum[tid >> 6] = v;
    __syncthreads();
    float add = 0.f;
    int wv = tid >> 6;
#pragma unroll
    for (int i = 0; i < 3; ++i)
        if (i < wv) add += wsum[i];
    acs[base] = v + add;
}

// ---------------- FUSED: SSD chunk states (0..767) + sraw tiles (768..1087)
__global__ __launch_bounds__(256) void ssd_states_sraw_k(const unsigned short* __restrict__ xc,
    const float* __restrict__ dtp, const float* __restrict__ acs_g,
    float* __restrict__ st, unsigned short* __restrict__ sraw)
{
    __shared__ float s_coef[256];
    __shared__ unsigned short SXT[64 * STS];
    __shared__ unsigned short SBT[128 * STS];
    int bid = blockIdx.x;
    int blk = (gridDim.x & 7) ? bid : ((bid & 7) * (gridDim.x >> 3) + (bid >> 3));
    int tid = threadIdx.x;
    int w = tid >> 6, l = tid & 63;
    int lr = l & 15, lk = l >> 4;
    if (blk >= BB * NC * NHH) {
        int t = blk - BB * NC * NHH;
        int bc = t / 10, tile = t % 10;
        int rem = tile, st_i = 0;
        for (st_i = 0; ; ++st_i) { if (rem < st_i + 1) break; rem -= st_i + 1; }
        int zt = rem;
        int b = bc / NC, c = bc % NC;
        size_t rowbase = (size_t)b * SEQ + c * CHK;
        for (int i = tid; i < 64 * 32; i += 256) {
            int r = i >> 5, c4 = (i & 31) * 4;
            *(ushort4*)&SXT[r * STS + c4] = *(const ushort4*)&xc[(rowbase + st_i * 64 + r) * CDIM + DSSM + DSTATE + c4];
            *(ushort4*)&SBT[r * STS + c4] = *(const ushort4*)&xc[(rowbase + zt * 64 + r) * CDIM + DSSM + c4];
        }
        __syncthreads();
        f32x4 d[4] = {};
        __builtin_amdgcn_s_setprio(1);
#pragma unroll
        for (int kt = 0; kt < 4; ++kt) {
            bf16x8 av = *(const bf16x8*)&SXT[(w * 16 + lr) * STS + kt * 32 + lk * 8];
            bf16x8 bv[4];
#pragma unroll
            for (int nj = 0; nj < 4; ++nj)
                bv[nj] = *(const bf16x8*)&SBT[(nj * 16 + lr) * STS + kt * 32 + lk * 8];
#pragma unroll
            for (int nj = 0; nj < 4; ++nj)
                d[nj] = __builtin_amdgcn_mfma_f32_16x16x32_bf16(av, bv[nj], d[nj], 0, 0, 0);
        }
        __builtin_amdgcn_s_setprio(0);
        unsigned short* tp = sraw + (size_t)bc * 16 * 4096 + (size_t)(st_i * 4 + zt) * 4096;
#pragma unroll
        for (int nj = 0; nj < 4; ++nj)
#pragma unroll
            for (int r = 0; r < 4; ++r)
                tp[(w * 16 + lk * 4 + r) * 64 + nj * 16 + lr] = f2bf(d[nj][r]);
        return;
    }
    int h = blk % NHH, c = (blk / NHH) % NC, b = blk / (NHH * NC);
    size_t rowbase = (size_t)b * SEQ + c * CHK;
    size_t dbase = (size_t)(b * NHH + h) * SEQ + c * CHK;
    float alv = acs_g[dbase + 255];
    s_coef[tid] = expf(alv - acs_g[dbase + tid]) * dtp[dbase + tid];
    __syncthreads();
    f32x4 acc[4][2] = {};
    for (int z0 = 0; z0 < CHK; z0 += 128) {
        if (z0) __syncthreads();
        for (int i = tid; i < 128 * 8; i += 256) {
            int zz = i >> 3, p8 = (i & 7) * 8;
            float sc = s_coef[z0 + zz];
            u16x8 v = *(const u16x8*)&xc[(rowbase + z0 + zz) * CDIM + h * HDIM + p8];
#pragma unroll
            for (int e = 0; e < 8; ++e)
                SXT[(p8 + e) * STS + zz] = f2bf(bf2f(v[e]) * sc);
        }
        for (int i = tid; i < 128 * 16; i += 256) {
            int zz = i >> 4, n8 = (i & 15) * 8;
            u16x8 v = *(const u16x8*)&xc[(rowbase + z0 + zz) * CDIM + DSSM + n8];
#pragma unroll
            for (int e = 0; e < 8; ++e)
                SBT[(n8 + e) * STS + zz] = v[e];
        }
        __syncthreads();
#pragma unroll
        for (int kt = 0; kt < 4; ++kt) {
            bf16x8 av[4], bv[2];
#pragma unroll
            for (int mi = 0; mi < 4; ++mi)
                av[mi] = *(const bf16x8*)&SXT[(mi * 16 + lr) * STS + kt * 32 + lk * 8];
#pragma unroll
            for (int nj = 0; nj < 2; ++nj)
                bv[nj] = *(const bf16x8*)&SBT[(w * 32 + nj * 16 + lr) * STS + kt * 32 + lk * 8];
#pragma unroll
            for (int mi = 0; mi < 4; ++mi)
#pragma unroll
                for (int nj = 0; nj < 2; ++nj)
                    acc[mi][nj] = __builtin_amdgcn_mfma_f32_16x16x32_bf16(av[mi], bv[nj], acc[mi][nj], 0, 0, 0);
        }
    }
    size_t base = (size_t)blk * (HDIM * DSTATE);
#pragma unroll
    for (int mi = 0; mi < 4; ++mi)
#pragma unroll
        for (int r = 0; r < 4; ++r) {
            int p = mi * 16 + lk * 4 + r;
#pragma unroll
            for (int nj = 0; nj < 2; ++nj)
                st[base + p * DSTATE + w * 32 + nj * 16 + lr] = acc[mi][nj][r];
        }
}

// ---------------- inter-chunk scan, 8x parallel over j-groups
__global__ __launch_bounds__(256) void ssd_scan_k(const float* __restrict__ st,
    const float* __restrict__ acs_g, unsigned short* __restrict__ pv16)
{
    int bh = blockIdx.x >> 3;
    int jg = blockIdx.x & 7;
    int b = bh / NHH, h = bh % NHH;
    int tid = threadIdx.x;
    float carry[4];
#pragma unroll
    for (int j = 0; j < 4; ++j) carry[j] = 0.f;
    for (int c = 0; c < NC; ++c) {
        int bch = (b * NC + c) * NHH + h;
        size_t base = (size_t)bch * (HDIM * DSTATE);
        float dcy = expf(acs_g[(size_t)(b * NHH + h) * SEQ + c * CHK + 255]);
#pragma unroll
        for (int j = 0; j < 4; ++j) {
            size_t idx = base + tid + (size_t)(jg * 4 + j) * 256;
            pv16[idx] = f2bf(carry[j]);
            carry[j] = fmaf(dcy, carry[j], st[idx]);
        }
    }
}

// ---------------- Y from S_raw; epilogue fuses gating g=y*silu(z), writes g,
// and accumulates per-row sum(g^2) via lane-reduce + atomicAdd (RMSNorm fold)
__global__ __launch_bounds__(256) void ssd_y2_k(const unsigned short* __restrict__ xc,
    const float* __restrict__ dtp, const float* __restrict__ acs_g,
    const unsigned short* __restrict__ sraw, const unsigned short* __restrict__ pv16,
    const float* __restrict__ Dp, const unsigned short* __restrict__ zbf,
    unsigned short* __restrict__ Ybf, float* __restrict__ ssb)
{
    __shared__ unsigned short SXT[32 * SXS];
    int bid = blockIdx.x;
    int blk2 = (gridDim.x & 7) ? bid : ((bid & 7) * (gridDim.x >> 3) + (bid >> 3));
    int half = blk2 & 1;
    int blk = blk2 >> 1;
    int h = blk % NHH;
    int c = (blk / NHH) % NC;
    int b = blk / (NHH * NC);
    int tid = threadIdx.x;
    int w = tid >> 6, l = tid & 63;
    int lr = l & 15, lk = l >> 4;
    int pbase = half * 32;
    size_t rowbase = (size_t)b * SEQ + c * CHK;
    size_t dbase = (size_t)(b * NHH + h) * SEQ + c * CHK;
    for (int i = tid; i < 256 * 4; i += 256) {
        int z = i >> 2, p8 = (i & 3) * 8;
        float az0q = acs_g[dbase + (z & 192)];
        float e = az0q - acs_g[dbase + z];
        if (e > 60.f) e = 60.f;
        float sc = expf(e) * dtp[dbase + z];
        u16x8 v = *(const u16x8*)&xc[(rowbase + z) * CDIM + h * HDIM + pbase + p8];
#pragma unroll
        for (int e2 = 0; e2 < 8; ++e2)
            SXT[(p8 + e2) * SXS + z] = f2bf(bf2f(v[e2]) * sc);
    }
    float az0w = acs_g[dbase + w * 64];
    float esw[4][4];
#pragma unroll
    for (int mi = 0; mi < 4; ++mi)
#pragma unroll
        for (int r = 0; r < 4; ++r)
            esw[mi][r] = expf(acs_g[dbase + w * 64 + mi * 16 + lk * 4 + r] - az0w);
    __syncthreads();

    const unsigned short* tbase = sraw + (size_t)(b * NC + c) * 16 * 4096;
    const unsigned short* pvbase = pv16 + (size_t)blk * (HDIM * DSTATE);
    f32x4 acc[4][2] = {};
    for (int zt = 0; zt < w; ++zt) {
        const unsigned short* tp = tbase + (size_t)(w * 4 + zt) * 4096;
        f32x4 tmp[4][2] = {};
        __builtin_amdgcn_s_setprio(1);
#pragma unroll
        for (int kt = 0; kt < 2; ++kt) {
            bf16x8 av[4], bv[2];
#pragma unroll
            for (int mi = 0; mi < 4; ++mi)
                av[mi] = *(const bf16x8*)&tp[(mi * 16 + lr) * 64 + kt * 32 + lk * 8];
#pragma unroll
            for (int nj = 0; nj < 2; ++nj)
                bv[nj] = *(const bf16x8*)&SXT[(nj * 16 + lr) * SXS + zt * 64 + kt * 32 + lk * 8];
#pragma unroll
            for (int mi = 0; mi < 4; ++mi)
#pragma unroll
                for (int nj = 0; nj < 2; ++nj)
                    tmp[mi][nj] = __builtin_amdgcn_mfma_f32_16x16x32_bf16(av[mi], bv[nj], tmp[mi][nj], 0, 0, 0);
        }
        __builtin_amdgcn_s_setprio(0);
        float rho = expf(az0w - acs_g[dbase + zt * 64]);
#pragma unroll
        for (int mi = 0; mi < 4; ++mi)
#pragma unroll
            for (int r = 0; r < 4; ++r) {
                float es = esw[mi][r] * rho;
#pragma unroll
                for (int nj = 0; nj < 2; ++nj)
                    acc[mi][nj][r] += es * tmp[mi][nj][r];
            }
    }
    {
        const unsigned short* tp = tbase + (size_t)(w * 4 + w) * 4096;
        f32x4 tmp[4][2] = {};
        __builtin_amdgcn_s_setprio(1);
#pragma unroll
        for (int kt = 0; kt < 2; ++kt) {
            bf16x8 av[4], bv[2];
#pragma unroll
            for (int mi = 0; mi < 4; ++mi) {
                av[mi] = *(const bf16x8*)&tp[(mi * 16 + lr) * 64 + kt * 32 + lk * 8];
                int zb = kt * 32 + lk * 8;
                int sl = mi * 16 + lr;
#pragma unroll
                for (int e = 0; e < 8; ++e)
                    if (zb + e > sl) av[mi][e] = 0;
            }
#pragma unroll
            for (int nj = 0; nj < 2; ++nj)
                bv[nj] = *(const bf16x8*)&SXT[(nj * 16 + lr) * SXS + w * 64 + kt * 32 + lk * 8];
#pragma unroll
            for (int mi = 0; mi < 4; ++mi)
#pragma unroll
                for (int nj = 0; nj < 2; ++nj)
                    tmp[mi][nj] = __builtin_amdgcn_mfma_f32_16x16x32_bf16(av[mi], bv[nj], tmp[mi][nj], 0, 0, 0);
        }
        __builtin_amdgcn_s_setprio(0);
#pragma unroll
        for (int mi = 0; mi < 4; ++mi)
#pragma unroll
            for (int r = 0; r < 4; ++r) {
                float es = esw[mi][r];
#pragma unroll
                for (int nj = 0; nj < 2; ++nj)
                    acc[mi][nj][r] += es * tmp[mi][nj][r];
            }
    }
    {
        f32x4 tmp[4][2] = {};
        __builtin_amdgcn_s_setprio(1);
#pragma unroll
        for (int kt = 0; kt < 4; ++kt) {
            bf16x8 av[4], bv[2];
#pragma unroll
            for (int mi = 0; mi < 4; ++mi)
                av[mi] = *(const bf16x8*)&xc[(rowbase + w * 64 + mi * 16 + lr) * CDIM + DSSM + DSTATE + kt * 32 + lk * 8];
#pragma unroll
            for (int nj = 0; nj < 2; ++nj)
                bv[nj] = *(const bf16x8*)&pvbase[(pbase + nj * 16 + lr) * DSTATE + kt * 32 + lk * 8];
#pragma unroll
            for (int mi = 0; mi < 4; ++mi)
#pragma unroll
                for (int nj = 0; nj < 2; ++nj)
                    tmp[mi][nj] = __builtin_amdgcn_mfma_f32_16x16x32_bf16(av[mi], bv[nj], tmp[mi][nj], 0, 0, 0);
        }
        __builtin_amdgcn_s_setprio(0);
        float eoff = expf(az0w);
#pragma unroll
        for (int mi = 0; mi < 4; ++mi)
#pragma unroll
            for (int r = 0; r < 4; ++r) {
                float es = esw[mi][r] * eoff;
#pragma unroll
                for (int nj = 0; nj < 2; ++nj)
                    acc[mi][nj][r] += es * tmp[mi][nj][r];
            }
    }
    float dph = Dp[h];
#pragma unroll
    for (int mi = 0; mi < 4; ++mi) {
#pragma unroll
        for (int r = 0; r < 4; ++r) {
            int s = w * 64 + mi * 16 + lk * 4 + r;
            size_t roff = rowbase + s;
            float gsq = 0.f;
#pragma unroll
            for (int nj = 0; nj < 2; ++nj) {
                int p = pbase + nj * 16 + lr;
                float xv = bf2f(xc[roff * CDIM + h * HDIM + p]);
                float yv = acc[mi][nj][r] + dph * xv;
                float zv = bf2f(zbf[roff * DSSM + h * HDIM + p]);
                float g = yv * siluf(zv);
                Ybf[roff * DSSM + h * HDIM + p] = f2bf(g);
                gsq = fmaf(g, g, gsq);
            }
#pragma unroll
            for (int mm = 1; mm < 16; mm <<= 1)
                gsq += __shfl_xor(gsq, mm, 64);
            if (lr == 0) atomicAdd(&ssb[roff], gsq);
        }
    }
}

// ---------------- MEGA3: out-proj GEMM (tri-buffered, swizzled, RMS row-scale
// in epilogue) + timeout segment
__global__ __launch_bounds__(256) void gemm_out_timeout_k(
    const unsigned short* __restrict__ A, const unsigned short* __restrict__ B,
    const float* __restrict__ bias, float* __restrict__ C, int N, int K, int KT, int NT, int NWGG,
    const float* __restrict__ ssb,
    const float* __restrict__ td, const float* __restrict__ tdt,
    const float* __restrict__ gw, const float* __restrict__ gb,
    const float* __restrict__ lnw, const float* __restrict__ lnb, float* __restrict__ out2)
{
    __shared__ __align__(16) unsigned char SMEMRAW[49152];
    unsigned short* SMEM = (unsigned short*)SMEMRAW;
    const int tid = threadIdx.x;
    int nwg = gridDim.x, bid = blockIdx.x;
    int wg = (nwg & 7) ? bid : ((bid & 7) * (nwg >> 3) + (bid >> 3));
    if (wg >= NWGG) {
        float* tm = (float*)SMEMRAW;
        __shared__ float red[8];
        int row = wg - NWGG;
        const float* tdr = td + (size_t)row * SEQ;
        const float* tdtr = tdt + (size_t)row * SEQ;
        int wv = tid >> 6, ln = tid & 63;
        float part = 0.f;
        for (int i = tid; i < SEQ; i += 256) part = fmaf(tdr[i], gw[i], part);
#pragma unroll
        for (int o = 32; o > 0; o >>= 1) part += __shfl_down(part, o, 64);
        if (ln == 0) red[wv] = part;
        __syncthreads();
        float dot = red[0] + red[1] + red[2] + red[3];
        float tg = 1.f / (1.f + expf(-(dot + gb[0])));
        __syncthreads();
        float sum = 0.f;
        for (int i = tid; i < SEQ; i += 256) {
            float x = tg * tdr[i] + (1.f - tg) * tdtr[i];
            tm[i] = x;
            sum += x;
        }
#pragma unroll
        for (int o = 32; o > 0; o >>= 1) sum += __shfl_down(sum, o, 64);
        if (ln == 0) red[wv] = sum;
        __syncthreads();
        float mu = (red[0] + red[1] + red[2] + red[3]) / (float)SEQ;
        __syncthreads();
        float s2 = 0.f;
        for (int i = tid; i < SEQ; i += 256) { float d = tm[i] - mu; s2 = fmaf(d, d, s2); }
#pragma unroll
        for (int o = 32; o > 0; o >>= 1) s2 += __shfl_down(s2, o, 64);
        if (ln == 0) red[wv] = s2;
        __syncthreads();
        float var = (red[0] + red[1] + red[2] + red[3]) / (float)SEQ;
        float inv = rsqrtf(var + 1e-12f);
        for (int i = tid; i < SEQ; i += 256)
            out2[(size_t)row * SEQ + i] = (tm[i] - mu) * inv * lnw[i] + lnb[i];
        return;
    }
    const int w = tid >> 6, l = tid & 63;
    const int wr = w >> 1, wc = w & 1;
    const int lr = l & 15, lk = l >> 4;
    const int lkx = lk ^ ((lr >> 1) & 3);
    const int m0 = (wg / NT) * 128, n0 = (wg % NT) * 128;
    f32x4 acc[4][4] = {};
    const int i16 = w * 64 + l;
    const int row0 = i16 >> 2, sl = i16 & 3;
    const int slx = sl ^ ((row0 >> 1) & 3);
    const size_t ga0 = (size_t)(m0 + row0) * K + slx * 8;
    const size_t ga1 = (size_t)(m0 + row0 + 64) * K + slx * 8;
    const size_t gb0 = (size_t)(n0 + row0) * K + slx * 8;
    const size_t gb1 = (size_t)(n0 + row0 + 64) * K + slx * 8;
    const int lo0 = (w * 64) * 8;
    const int lo1 = (256 + w * 64) * 8;

#define STAGE3(bb, kt) { int ko = (kt) * 32; int bs = (bb) * 8192;           \
      gload_lds16(A + ga0 + ko, &SMEM[bs + lo0]);                            \
      gload_lds16(A + ga1 + ko, &SMEM[bs + lo1]);                            \
      gload_lds16(B + gb0 + ko, &SMEM[bs + 4096 + lo0]);                     \
      gload_lds16(B + gb1 + ko, &SMEM[bs + 4096 + lo1]); }

    STAGE3(0, 0);
    STAGE3(1, 1);
    for (int kt = 0; kt < KT; ++kt) {
        if (kt + 1 < KT) {
            asm volatile("s_waitcnt vmcnt(4)" ::: "memory");
        } else {
            asm volatile("s_waitcnt vmcnt(0)" ::: "memory");
        }
        __builtin_amdgcn_s_barrier();
        if (kt + 2 < KT) STAGE3((kt + 2) % 3, kt + 2);
        int bs = (kt % 3) * 8192;
        bf16x8 af[4], bg[4];
#pragma unroll
        for (int mi = 0; mi < 4; ++mi)
            af[mi] = *(const bf16x8*)&SMEM[bs + (wr * 64 + mi * 16 + lr) * 32 + lkx * 8];
#pragma unroll
        for (int nj = 0; nj < 4; ++nj)
            bg[nj] = *(const bf16x8*)&SMEM[bs + 4096 + (wc * 64 + nj * 16 + lr) * 32 + lkx * 8];
#pragma unroll
        for (int mi = 0; mi < 4; ++mi)
#pragma unroll
            for (int nj = 0; nj < 4; ++nj)
                acc[mi][nj] = __builtin_amdgcn_mfma_f32_16x16x32_bf16(af[mi], bg[nj], acc[mi][nj], 0, 0, 0);
    }
#undef STAGE3
    float scr[4][4];
#pragma unroll
    for (int mi = 0; mi < 4; ++mi)
#pragma unroll
        for (int r = 0; r < 4; ++r) {
            int m = m0 + wr * 64 + mi * 16 + lk * 4 + r;
            scr[mi][r] = rsqrtf(ssb[m] * (1.0f / (float)DSSM) + 1e-12f);
        }
#pragma unroll
    for (int nj = 0; nj < 4; ++nj) {
        int col = n0 + wc * 64 + nj * 16 + lr;
        float bz = bias[col];
#pragma unroll
        for (int mi = 0; mi < 4; ++mi) {
#pragma unroll
            for (int r = 0; r < 4; ++r) {
                int m = m0 + wr * 64 + mi * 16 + lk * 4 + r;
                C[(size_t)m * N + col] = acc[mi][nj][r] * scr[mi][r] + bz;
            }
        }
    }
}

extern "C" void kernel_launch(void* const* d_in, const int* in_sizes, int n_in,
                              void* d_out, int out_size, void* d_ws, size_t ws_size,
                              hipStream_t stream)
{
    const float* u      = (const float*)d_in[0];
    const float* td     = (const float*)d_in[1];
    const float* W_in   = (const float*)d_in[2];
    const float* b_in   = (const float*)d_in[3];
    const float* conv_w = (const float*)d_in[4];
    const float* conv_b = (const float*)d_in[5];
    const float* t1w    = (const float*)d_in[6];
    const float* t1b    = (const float*)d_in[7];
    const float* t2w    = (const float*)d_in[8];
    const float* t2b    = (const float*)d_in[9];
    const float* m1w    = (const float*)d_in[10];
    const float* m1b    = (const float*)d_in[11];
    const float* m2w    = (const float*)d_in[12];
    const float* m2b    = (const float*)d_in[13];
    const float* gw     = (const float*)d_in[14];
    const float* gb     = (const float*)d_in[15];
    const float* lnw    = (const float*)d_in[16];
    const float* lnb    = (const float*)d_in[17];
    const float* A_log  = (const float*)d_in[18];
    const float* dt_bias= (const float*)d_in[19];
    const float* Dpv    = (const float*)d_in[20];
    const float* nw     = (const float*)d_in[21];
    const float* W_out  = (const float*)d_in[22];
    const float* b_out  = (const float*)d_in[23];
    float* out  = (float*)d_out;
    float* out2 = out + (size_t)MR * DMODEL;

    float* ws = (float*)d_ws;
    size_t o = 0;
    float* zbuf  = ws + o; o += (size_t)MR * DSSM;
    float* r1    = ws + o; o += (size_t)MR * DSSM;
    float* xcv   = ws + o; o += (size_t)MR * CDIM / 2;
    float* partb = ws + o; o += (size_t)KSPLIT * 48 * SEQ;
    float* hid   = ws + o; o += (size_t)BB * NHH * SEQ;
    float* tss   = ws + o; o += (size_t)BB * NHH * SEQ;
    float* tdt   = ws + o; o += (size_t)BB * NHH * SEQ;
    float* dtp   = ws + o; o += (size_t)MR * NHH;
    float* acs_g = ws + o; o += (size_t)MR * NHH;
    float* ssb   = ws + o; o += (size_t)MR;
    float* pvb   = ws + o; o += (size_t)BB * NC * NHH * HDIM * DSTATE;
    unsigned short* sraw = (unsigned short*)(ws + o); o += (size_t)BB * NC * 16 * 4096 / 2;
    unsigned short* r1b = (unsigned short*)r1;
    float* stb = r1;
    unsigned short* ybf16 = (unsigned short*)r1;
    unsigned short* xcv_bf = (unsigned short*)xcv;
    unsigned short* u_bf  = (unsigned short*)pvb;
    unsigned short* Wi_bf = (unsigned short*)(pvb + 3145728);
    unsigned short* pv16  = (unsigned short*)pvb;
    unsigned short* zbf   = (unsigned short*)zbuf;
    unsigned short* Wo_bf = (unsigned short*)(zbuf + 6291456);

    dim3 blk(256);
    const int NWG1 = (XSTR / 128) * (MR / 128);          // 960
    const int NWGD = NWG1 + (DSSM / 128) * (MR / 128);   // 1728
    const int NWGSK = (SEQ / 128) * KSPLIT;              // 1024
    const int NWGC = 448 * (MR / CT) / 256;              // 896
    const int NB0 = MR * DMODEL / 1024;                  // 6144
    const int NB1 = 3456 * DMODEL / 1024;                // 2592
    const int NB2 = DMODEL * DSSM / 1024;                // 1152

    cvt3_k<<<dim3(NB0 + NB1 + NB2), blk, 0, stream>>>(
        u, u_bf, NB0, MR * DMODEL,
        W_in, Wi_bf, NB1, DPROJ * DMODEL,
        W_out, Wo_bf, NB2, DMODEL * DSSM, nw);
    // --- MEGA1: dual in-proj GEMM (LDS tri-buffered) + skinny1 ---
    gemm_dual_skinny<<<dim3(NWGD + NWGSK), blk, 0, stream>>>(
        u_bf,
        Wi_bf + (size_t)DSSM * DMODEL, b_in + DSSM, r1b, XSTR, XSTR / 128, DPROJ - DSSM, NWG1,
        Wi_bf, b_in, zbf, DSSM, DSSM / 128, DSSM,
        DMODEL, DMODEL / 32, NWGD,
        td, m1w, partb, SEQ, SEQ);
    reduce_part_k<<<dim3((48 * SEQ + 255) / 256), blk, 0, stream>>>(partb, m1b, hid, SEQ, 1);
    // --- MEGA2: conv + skinny2 (hid @ m2w) ---
    conv_skinny2_k<<<dim3(NWGC + NWGSK), blk, 0, stream>>>(
        r1b, conv_w, conv_b, xcv_bf, hid, m2w, partb, SEQ, SEQ, NWGC);
    reduce_part_k<<<dim3((48 * SEQ + 255) / 256), blk, 0, stream>>>(partb, m2b, tss, SEQ, 0);
    time_conv_k<<<dim3(BB * NHH * 4), blk, 0, stream>>>(tss, td, t1w, t1b, t2w, t2b, tdt);
    dtsp_cum_k<<<dim3(BB * NHH * NC), blk, 0, stream>>>(r1b, tdt, dt_bias, A_log, dtp, acs_g, ssb);
    ssd_states_sraw_k<<<dim3(BB * NC * NHH + BB * NC * 10), blk, 0, stream>>>(xcv_bf, dtp, acs_g, stb, sraw);
    ssd_scan_k<<<dim3(BB * NHH * 8), blk, 0, stream>>>(stb, acs_g, pv16);
    ssd_y2_k<<<dim3(BB * NC * NHH * 2), blk, 0, stream>>>(xcv_bf, dtp, acs_g, sraw, pv16, Dpv, zbf, ybf16, ssb);
    // --- MEGA3: out-proj GEMM (A = gated un-normalized g; nw folded into Wo;
    //            row rsqrt scale applied in epilogue) + timeout ---
    gemm_out_timeout_k<<<dim3((DMODEL / 128) * (MR / 128) + BB * NHH), blk, 0, stream>>>(
        ybf16, Wo_bf, b_out, out, DMODEL, DSSM, DSSM / 32, DMODEL / 128, (DMODEL / 128) * (MR / 128),
        ssb, td, tdt, gw, gb, lnw, lnb, out2);
}

// Round 34
// 302.720 us; speedup vs baseline: 1.0523x; 1.0523x over previous
//
#include <hip/hip_runtime.h>
#include <math.h>

#define BB 2
#define SEQ 4096
#define DMODEL 768
#define DSTATE 128
#define NHH 24
#define HDIM 64
#define DSSM 1536
#define CDIM 1792
#define CHK 256
#define NC 16
#define DPROJ 3352
#define MR (BB*SEQ)
#define KSPLIT 32
#define XSTR 1920
#define CT 16
#define SXS 270
#define STS 134

typedef __attribute__((ext_vector_type(8))) short bf16x8;
typedef __attribute__((ext_vector_type(8))) unsigned short u16x8;
typedef __attribute__((ext_vector_type(4))) float f32x4;

__device__ __forceinline__ float siluf(float x) { return x / (1.0f + expf(-x)); }

__device__ __forceinline__ unsigned short f2bf(float f) {
    unsigned u = __float_as_uint(f);
    unsigned r = (u + 0x7fffu + ((u >> 16) & 1u)) >> 16;
    return (unsigned short)r;
}

__device__ __forceinline__ float bf2f(unsigned short u) {
    return __uint_as_float(((unsigned)u) << 16);
}

__device__ __forceinline__ float4 bf2f4(ushort4 v) {
    float4 o;
    o.x = bf2f(v.x); o.y = bf2f(v.y); o.z = bf2f(v.z); o.w = bf2f(v.w);
    return o;
}

__device__ __forceinline__ bf16x8 pack8(float4 a, float4 b) {
    u16x8 r;
    r[0] = f2bf(a.x); r[1] = f2bf(a.y); r[2] = f2bf(a.z); r[3] = f2bf(a.w);
    r[4] = f2bf(b.x); r[5] = f2bf(b.y); r[6] = f2bf(b.z); r[7] = f2bf(b.w);
    return *(bf16x8*)&r;
}

__device__ __forceinline__ void gload_lds16(const void* g, void* l) {
    __builtin_amdgcn_global_load_lds((const __attribute__((address_space(1))) unsigned int*)g,
                                     (__attribute__((address_space(3))) unsigned int*)l, 16, 0, 0);
}

// ---------------- f32 -> bf16 conversion, 3 tensors in one launch
__global__ __launch_bounds__(256) void cvt3_k(
    const float* __restrict__ in0, unsigned short* __restrict__ out0, int nb0, int nv0,
    const float* __restrict__ in1, unsigned short* __restrict__ out1, int nb1, int nv1,
    const float* __restrict__ in2, unsigned short* __restrict__ out2, int nb2, int nv2)
{
    int b = blockIdx.x;
    const float* in; unsigned short* out; int nvalid; int base;
    if (b < nb0) { in = in0; out = out0; nvalid = nv0; base = b; }
    else if (b < nb0 + nb1) { in = in1; out = out1; nvalid = nv1; base = b - nb0; }
    else { in = in2; out = out2; nvalid = nv2; base = b - nb0 - nb1; }
    int i = (base * 256 + threadIdx.x) * 4;
    ushort4 o;
    if (i + 3 < nvalid) {
        float4 v = *(const float4*)&in[i];
        o.x = f2bf(v.x); o.y = f2bf(v.y); o.z = f2bf(v.z); o.w = f2bf(v.w);
    } else {
        o.x = (i + 0 < nvalid) ? f2bf(in[i + 0]) : 0;
        o.y = (i + 1 < nvalid) ? f2bf(in[i + 1]) : 0;
        o.z = (i + 2 < nvalid) ? f2bf(in[i + 2]) : 0;
        o.w = (i + 3 < nvalid) ? f2bf(in[i + 3]) : 0;
    }
    *(ushort4*)&out[i] = o;
}

// ---------------- MEGA1: DUAL bf16 GEMM 128x128 (tri-buffered, swizzled) + skinny1 MFMA
__global__ __launch_bounds__(256) void gemm_dual_skinny(
    const unsigned short* __restrict__ A,
    const unsigned short* __restrict__ B1, const float* __restrict__ bias1,
    unsigned short* __restrict__ C1, int N1, int NT1, int nbias1, int NWG1,
    const unsigned short* __restrict__ B2, const float* __restrict__ bias2,
    unsigned short* __restrict__ C2, int N2, int NT2, int nbias2,
    int K, int KT, int NWGD,
    const float* __restrict__ skA, const float* __restrict__ skB,
    float* __restrict__ skPart, int skN, int skK)
{
    __shared__ unsigned short SMEM[24576];   // 3 bufs x 8192 ushorts = 48KB
    const int tid = threadIdx.x;
    const int w = tid >> 6, l = tid & 63;
    const int lr = l & 15, lk = l >> 4;
    int nwg = gridDim.x, bid = blockIdx.x;
    int wg = (nwg & 7) ? bid : ((bid & 7) * (nwg >> 3) + (bid >> 3));
    if (wg >= NWGD) {
        // ---- skinny1 path: M=48 split-K(32) MFMA, LDS-free ----
        int t = wg - NWGD;
        int nb = t & 31, kb = t >> 5;
        const int n0s = nb * 128;
        const int KS = skK / KSPLIT;          // 128
        const int k0 = kb * KS;
        const int nw0 = n0s + w * 32;
        f32x4 sacc[3][2] = {};
        for (int kt = 0; kt < KS; kt += 32) {
            int kk = k0 + kt + lk * 8;
            bf16x8 af[3], bfr[2];
#pragma unroll
            for (int mi = 0; mi < 3; ++mi) {
                const float* ap = &skA[(size_t)(mi * 16 + lr) * skK + kk];
                af[mi] = pack8(*(const float4*)ap, *(const float4*)(ap + 4));
            }
#pragma unroll
            for (int nf = 0; nf < 2; ++nf) {
                const float* bp = &skB[(size_t)(nw0 + nf * 16 + lr) * skK + kk];
                bfr[nf] = pack8(*(const float4*)bp, *(const float4*)(bp + 4));
            }
#pragma unroll
            for (int mi = 0; mi < 3; ++mi)
#pragma unroll
                for (int nf = 0; nf < 2; ++nf)
                    sacc[mi][nf] = __builtin_amdgcn_mfma_f32_16x16x32_bf16(af[mi], bfr[nf], sacc[mi][nf], 0, 0, 0);
        }
        float* pb = skPart + (size_t)kb * 48 * skN;
#pragma unroll
        for (int mi = 0; mi < 3; ++mi)
#pragma unroll
            for (int r = 0; r < 4; ++r)
#pragma unroll
                for (int nf = 0; nf < 2; ++nf)
                    pb[(size_t)(mi * 16 + lk * 4 + r) * skN + nw0 + nf * 16 + lr] = sacc[mi][nf][r];
        return;
    }
    // ---- dual GEMM path ----
    const int wr = w >> 1, wc = w & 1;
    const int lkx = lk ^ ((lr >> 1) & 3);
    const unsigned short* B;
    const float* bias;
    unsigned short* C;
    int N, NT, nbias;
    if (wg < NWG1) { B = B1; bias = bias1; C = C1; N = N1; NT = NT1; nbias = nbias1; }
    else { wg -= NWG1; B = B2; bias = bias2; C = C2; N = N2; NT = NT2; nbias = nbias2; }
    const int m0 = (wg / NT) * 128, n0 = (wg % NT) * 128;
    f32x4 acc[4][4] = {};
    const int i16 = w * 64 + l;
    const int row0 = i16 >> 2, sl = i16 & 3;
    const int slx = sl ^ ((row0 >> 1) & 3);
    const size_t ga0 = (size_t)(m0 + row0) * K + slx * 8;
    const size_t ga1 = (size_t)(m0 + row0 + 64) * K + slx * 8;
    const size_t gb0 = (size_t)(n0 + row0) * K + slx * 8;
    const size_t gb1 = (size_t)(n0 + row0 + 64) * K + slx * 8;
    const int lo0 = (w * 64) * 8;
    const int lo1 = (256 + w * 64) * 8;

#define STAGE(bb, kt) { int ko = (kt) * 32; int bs = (bb) * 8192;            \
      gload_lds16(A + ga0 + ko, &SMEM[bs + lo0]);                            \
      gload_lds16(A + ga1 + ko, &SMEM[bs + lo1]);                            \
      gload_lds16(B + gb0 + ko, &SMEM[bs + 4096 + lo0]);                     \
      gload_lds16(B + gb1 + ko, &SMEM[bs + 4096 + lo1]); }

    STAGE(0, 0);
    STAGE(1, 1);
    for (int kt = 0; kt < KT; ++kt) {
        if (kt + 1 < KT) {
            asm volatile("s_waitcnt vmcnt(4)" ::: "memory");
        } else {
            asm volatile("s_waitcnt vmcnt(0)" ::: "memory");
        }
        __builtin_amdgcn_s_barrier();
        if (kt + 2 < KT) STAGE((kt + 2) % 3, kt + 2);
        int bs = (kt % 3) * 8192;
        bf16x8 af[4], bg[4];
#pragma unroll
        for (int mi = 0; mi < 4; ++mi)
            af[mi] = *(const bf16x8*)&SMEM[bs + (wr * 64 + mi * 16 + lr) * 32 + lkx * 8];
#pragma unroll
        for (int nj = 0; nj < 4; ++nj)
            bg[nj] = *(const bf16x8*)&SMEM[bs + 4096 + (wc * 64 + nj * 16 + lr) * 32 + lkx * 8];
#pragma unroll
        for (int mi = 0; mi < 4; ++mi)
#pragma unroll
            for (int nj = 0; nj < 4; ++nj)
                acc[mi][nj] = __builtin_amdgcn_mfma_f32_16x16x32_bf16(af[mi], bg[nj], acc[mi][nj], 0, 0, 0);
    }
#undef STAGE
    {
        unsigned short* CL = SMEM;
#pragma unroll
        for (int half = 0; half < 2; ++half) {
            __syncthreads();
            if (wr == half) {
#pragma unroll
                for (int nj = 0; nj < 4; ++nj) {
                    int col = n0 + wc * 64 + nj * 16 + lr;
                    float bz = (col < nbias) ? bias[col] : 0.f;
                    int cl = wc * 64 + nj * 16 + lr;
#pragma unroll
                    for (int mi = 0; mi < 4; ++mi)
#pragma unroll
                        for (int r = 0; r < 4; ++r)
                            CL[(mi * 16 + lk * 4 + r) * 136 + cl] = f2bf(acc[mi][nj][r] + bz);
                }
            }
            __syncthreads();
            for (int i = tid; i < 1024; i += 256) {
                int rr = i >> 4, c8 = (i & 15) * 8;
                int m = m0 + half * 64 + rr;
                *(u16x8*)&C[(size_t)m * N + n0 + c8] = *(const u16x8*)&CL[rr * 136 + c8];
            }
        }
    }
}

// ---------------- MEGA2: conv (blocks 0..895) + skinny2 MFMA (896..1919)
__global__ __launch_bounds__(256) void conv_skinny2_k(const unsigned short* __restrict__ xbc,
    const float* __restrict__ cw, const float* __restrict__ cb,
    unsigned short* __restrict__ out,
    const float* __restrict__ skA, const float* __restrict__ skB,
    float* __restrict__ skPart, int skN, int skK, int NWGC)
{
    int bid = blockIdx.x;
    int tid = threadIdx.x;
    if (bid >= NWGC) {
        int t = bid - NWGC;
        int nb = t & 31, kb = t >> 5;
        const int n0s = nb * 128;
        const int KS = skK / KSPLIT;
        const int k0 = kb * KS;
        const int w = tid >> 6, l = tid & 63;
        const int lr = l & 15, lk = l >> 4;
        const int nw0 = n0s + w * 32;
        f32x4 sacc[3][2] = {};
        for (int kt = 0; kt < KS; kt += 32) {
            int kk = k0 + kt + lk * 8;
            bf16x8 af[3], bfr[2];
#pragma unroll
            for (int mi = 0; mi < 3; ++mi) {
                const float* ap = &skA[(size_t)(mi * 16 + lr) * skK + kk];
                af[mi] = pack8(*(const float4*)ap, *(const float4*)(ap + 4));
            }
#pragma unroll
            for (int nf = 0; nf < 2; ++nf) {
                const float* bp = &skB[(size_t)(nw0 + nf * 16 + lr) * skK + kk];
                bfr[nf] = pack8(*(const float4*)bp, *(const float4*)(bp + 4));
            }
#pragma unroll
            for (int mi = 0; mi < 3; ++mi)
#pragma unroll
                for (int nf = 0; nf < 2; ++nf)
                    sacc[mi][nf] = __builtin_amdgcn_mfma_f32_16x16x32_bf16(af[mi], bfr[nf], sacc[mi][nf], 0, 0, 0);
        }
        float* pb = skPart + (size_t)kb * 48 * skN;
#pragma unroll
        for (int mi = 0; mi < 3; ++mi)
#pragma unroll
            for (int r = 0; r < 4; ++r)
#pragma unroll
                for (int nf = 0; nf < 2; ++nf)
                    pb[(size_t)(mi * 16 + lk * 4 + r) * skN + nw0 + nf * 16 + lr] = sacc[mi][nf][r];
        return;
    }
    // ---- conv path ----
    int idx = bid * 256 + tid;
    int slot = idx % 448;
    int g = idx / 448;
    int c4 = slot * 4;
    int b = g / (SEQ / CT);
    int t0 = (g % (SEQ / CT)) * CT;
    size_t rb = (size_t)b * SEQ;
    float4 cw0 = *(const float4*)&cw[(c4 + 0) * 4];
    float4 cw1 = *(const float4*)&cw[(c4 + 1) * 4];
    float4 cw2 = *(const float4*)&cw[(c4 + 2) * 4];
    float4 cw3 = *(const float4*)&cw[(c4 + 3) * 4];
    float4 cbv = *(const float4*)&cb[c4];
    float4 zero = {0.f, 0.f, 0.f, 0.f};
    float4 w0, w1, w2;
    w0 = (t0 - 3 >= 0) ? bf2f4(*(const ushort4*)&xbc[(rb + t0 - 3) * XSTR + c4]) : zero;
    w1 = (t0 - 2 >= 0) ? bf2f4(*(const ushort4*)&xbc[(rb + t0 - 2) * XSTR + c4]) : zero;
    w2 = (t0 - 1 >= 0) ? bf2f4(*(const ushort4*)&xbc[(rb + t0 - 1) * XSTR + c4]) : zero;
#pragma unroll
    for (int i = 0; i < CT; ++i) {
        int t = t0 + i;
        float4 w3 = bf2f4(*(const ushort4*)&xbc[(rb + t) * XSTR + c4]);
        float a0 = cbv.x + w0.x * cw0.x + w1.x * cw0.y + w2.x * cw0.z + w3.x * cw0.w;
        float a1 = cbv.y + w0.y * cw1.x + w1.y * cw1.y + w2.y * cw1.z + w3.y * cw1.w;
        float a2 = cbv.z + w0.z * cw2.x + w1.z * cw2.y + w2.z * cw2.z + w3.z * cw2.w;
        float a3 = cbv.w + w0.w * cw3.x + w1.w * cw3.y + w2.w * cw3.z + w3.w * cw3.w;
        ushort4 o;
        o.x = f2bf(siluf(a0)); o.y = f2bf(siluf(a1));
        o.z = f2bf(siluf(a2)); o.w = f2bf(siluf(a3));
        *(ushort4*)&out[(rb + t) * CDIM + c4] = o;
        w0 = w1; w1 = w2; w2 = w3;
    }
}

// ---------------- reduce split-K partials + bias (+ optional silu)
__global__ __launch_bounds__(256) void reduce_part_k(const float* __restrict__ part,
    const float* __restrict__ bias, float* __restrict__ out, int N, int act)
{
    int idx = blockIdx.x * 256 + threadIdx.x;
    if (idx >= 48 * N) return;
    int n = idx % N;
    float s = bias[n];
#pragma unroll
    for (int kb = 0; kb < KSPLIT; ++kb) s += part[(size_t)kb * 48 * N + idx];
    if (act) s = siluf(s);
    out[idx] = s;
}

// ---------------- per-(b,h) row, chunked over SEQ (4 chunks x 1024, halo 6):
// tdt0 = ts*td; conv1+silu; conv2+silu  (FIR convs -> chunking exact)
__global__ __launch_bounds__(256) void time_conv_k(const float* __restrict__ ts,
    const float* __restrict__ td, const float* __restrict__ w1, const float* __restrict__ b1,
    const float* __restrict__ w2, const float* __restrict__ b2, float* __restrict__ tdt)
{
    __shared__ float u0[1030];
    __shared__ float u1[1027];
    int row = blockIdx.x >> 2;
    int cq = blockIdx.x & 3;
    int h = row % NHH;
    int t0 = cq * 1024;
    const float* tsr = ts + (size_t)row * SEQ;
    const float* tdr = td + (size_t)row * SEQ;
    for (int j = threadIdx.x; j < 1030; j += 256) {
        int t = t0 - 6 + j;
        u0[j] = (t >= 0 && t < SEQ) ? tsr[t] * tdr[t] : 0.f;
    }
    __syncthreads();
    float wa[4], wb[4];
#pragma unroll
    for (int k = 0; k < 4; ++k) { wa[k] = w1[h * 4 + k]; wb[k] = w2[h * 4 + k]; }
    float ba = b1[h], bbv = b2[h];
    for (int j = threadIdx.x; j < 1027; j += 256) {
        int t = t0 - 3 + j;
        float acc = ba;
#pragma unroll
        for (int k = 0; k < 4; ++k) acc = fmaf(u0[j + k], wa[k], acc);
        u1[j] = (t >= 0) ? siluf(acc) : 0.f;
    }
    __syncthreads();
    for (int j = threadIdx.x; j < 1024; j += 256) {
        int t = t0 + j;
        float acc = bbv;
#pragma unroll
        for (int k = 0; k < 4; ++k) acc = fmaf(u1[j + k], wb[k], acc);
        tdt[(size_t)row * SEQ + t] = siluf(acc);
    }
}

// ---------------- fused: dt_sp softplus + per-chunk cumsum acs
__global__ __launch_bounds__(256) void dtsp_cum_k(const unsigned short* __restrict__ r1,
    const float* __restrict__ tdt, const float* __restrict__ dt_bias,
    const float* __restrict__ A_log, float* __restrict__ dtp, float* __restrict__ acs)
{
    __shared__ float wsum[4];
    int blk = blockIdx.x;
    int c = blk % NC;
    int bh = blk / NC;
    int h = bh % NHH, b = bh / NHH;
    int tid = threadIdx.x;
    int s = c * CHK + tid;
    size_t base = (size_t)bh * SEQ + s;
    float x = bf2f(r1[((size_t)(b * SEQ + s)) * XSTR + CDIM + h]) * tdt[base] + dt_bias[h];
    float dt = (x > 20.0f) ? x : log1pf(expf(x));
    dtp[base] = dt;
    float Ah = -expf(A_log[h]);
    float v = Ah * dt;
    int ln = tid & 63;
#pragma unroll
    for (int off = 1; off < 64; off <<= 1) {
        float t = __shfl_up(v, off, 64);
        if (ln >= off) v += t;
    }
    if (ln == 63) wsum[tid >> 6] = v;
    __syncthreads();
    float add = 0.f;
    int wv = tid >> 6;
#pragma unroll
    for (int i = 0; i < 3; ++i)
        if (i < wv) add += wsum[i];
    acs[base] = v + add;
}

// ---------------- FUSED: SSD chunk states (0..767) + sraw tiles (768..1087)
__global__ __launch_bounds__(256) void ssd_states_sraw_k(const unsigned short* __restrict__ xc,
    const float* __restrict__ dtp, const float* __restrict__ acs_g,
    float* __restrict__ st, unsigned short* __restrict__ sraw)
{
    __shared__ float s_coef[256];
    __shared__ unsigned short SXT[64 * STS];
    __shared__ unsigned short SBT[128 * STS];
    int bid = blockIdx.x;
    int blk = (gridDim.x & 7) ? bid : ((bid & 7) * (gridDim.x >> 3) + (bid >> 3));
    int tid = threadIdx.x;
    int w = tid >> 6, l = tid & 63;
    int lr = l & 15, lk = l >> 4;
    if (blk >= BB * NC * NHH) {
        int t = blk - BB * NC * NHH;
        int bc = t / 10, tile = t % 10;
        int rem = tile, st_i = 0;
        for (st_i = 0; ; ++st_i) { if (rem < st_i + 1) break; rem -= st_i + 1; }
        int zt = rem;
        int b = bc / NC, c = bc % NC;
        size_t rowbase = (size_t)b * SEQ + c * CHK;
        for (int i = tid; i < 64 * 32; i += 256) {
            int r = i >> 5, c4 = (i & 31) * 4;
            *(ushort4*)&SXT[r * STS + c4] = *(const ushort4*)&xc[(rowbase + st_i * 64 + r) * CDIM + DSSM + DSTATE + c4];
            *(ushort4*)&SBT[r * STS + c4] = *(const ushort4*)&xc[(rowbase + zt * 64 + r) * CDIM + DSSM + c4];
        }
        __syncthreads();
        f32x4 d[4] = {};
        __builtin_amdgcn_s_setprio(1);
#pragma unroll
        for (int kt = 0; kt < 4; ++kt) {
            bf16x8 av = *(const bf16x8*)&SXT[(w * 16 + lr) * STS + kt * 32 + lk * 8];
            bf16x8 bv[4];
#pragma unroll
            for (int nj = 0; nj < 4; ++nj)
                bv[nj] = *(const bf16x8*)&SBT[(nj * 16 + lr) * STS + kt * 32 + lk * 8];
#pragma unroll
            for (int nj = 0; nj < 4; ++nj)
                d[nj] = __builtin_amdgcn_mfma_f32_16x16x32_bf16(av, bv[nj], d[nj], 0, 0, 0);
        }
        __builtin_amdgcn_s_setprio(0);
        unsigned short* tp = sraw + (size_t)bc * 16 * 4096 + (size_t)(st_i * 4 + zt) * 4096;
#pragma unroll
        for (int nj = 0; nj < 4; ++nj)
#pragma unroll
            for (int r = 0; r < 4; ++r)
                tp[(w * 16 + lk * 4 + r) * 64 + nj * 16 + lr] = f2bf(d[nj][r]);
        return;
    }
    int h = blk % NHH, c = (blk / NHH) % NC, b = blk / (NHH * NC);
    size_t rowbase = (size_t)b * SEQ + c * CHK;
    size_t dbase = (size_t)(b * NHH + h) * SEQ + c * CHK;
    float alv = acs_g[dbase + 255];
    s_coef[tid] = expf(alv - acs_g[dbase + tid]) * dtp[dbase + tid];
    __syncthreads();
    f32x4 acc[4][2] = {};
    for (int z0 = 0; z0 < CHK; z0 += 128) {
        if (z0) __syncthreads();
        for (int i = tid; i < 128 * 8; i += 256) {
            int zz = i >> 3, p8 = (i & 7) * 8;
            float sc = s_coef[z0 + zz];
            u16x8 v = *(const u16x8*)&xc[(rowbase + z0 + zz) * CDIM + h * HDIM + p8];
#pragma unroll
            for (int e = 0; e < 8; ++e)
                SXT[(p8 + e) * STS + zz] = f2bf(bf2f(v[e]) * sc);
        }
        for (int i = tid; i < 128 * 16; i += 256) {
            int zz = i >> 4, n8 = (i & 15) * 8;
            u16x8 v = *(const u16x8*)&xc[(rowbase + z0 + zz) * CDIM + DSSM + n8];
#pragma unroll
            for (int e = 0; e < 8; ++e)
                SBT[(n8 + e) * STS + zz] = v[e];
        }
        __syncthreads();
#pragma unroll
        for (int kt = 0; kt < 4; ++kt) {
            bf16x8 av[4], bv[2];
#pragma unroll
            for (int mi = 0; mi < 4; ++mi)
                av[mi] = *(const bf16x8*)&SXT[(mi * 16 + lr) * STS + kt * 32 + lk * 8];
#pragma unroll
            for (int nj = 0; nj < 2; ++nj)
                bv[nj] = *(const bf16x8*)&SBT[(w * 32 + nj * 16 + lr) * STS + kt * 32 + lk * 8];
#pragma unroll
            for (int mi = 0; mi < 4; ++mi)
#pragma unroll
                for (int nj = 0; nj < 2; ++nj)
                    acc[mi][nj] = __builtin_amdgcn_mfma_f32_16x16x32_bf16(av[mi], bv[nj], acc[mi][nj], 0, 0, 0);
        }
    }
    size_t base = (size_t)blk * (HDIM * DSTATE);
#pragma unroll
    for (int mi = 0; mi < 4; ++mi)
#pragma unroll
        for (int r = 0; r < 4; ++r) {
            int p = mi * 16 + lk * 4 + r;
#pragma unroll
            for (int nj = 0; nj < 2; ++nj)
                st[base + p * DSTATE + w * 32 + nj * 16 + lr] = acc[mi][nj][r];
        }
}

// ---------------- inter-chunk scan, 8x parallel over j-groups
__global__ __launch_bounds__(256) void ssd_scan_k(const float* __restrict__ st,
    const float* __restrict__ acs_g, unsigned short* __restrict__ pv16)
{
    int bh = blockIdx.x >> 3;
    int jg = blockIdx.x & 7;
    int b = bh / NHH, h = bh % NHH;
    int tid = threadIdx.x;
    float carry[4];
#pragma unroll
    for (int j = 0; j < 4; ++j) carry[j] = 0.f;
    for (int c = 0; c < NC; ++c) {
        int bch = (b * NC + c) * NHH + h;
        size_t base = (size_t)bch * (HDIM * DSTATE);
        float dcy = expf(acs_g[(size_t)(b * NHH + h) * SEQ + c * CHK + 255]);
#pragma unroll
        for (int j = 0; j < 4; ++j) {
            size_t idx = base + tid + (size_t)(jg * 4 + j) * 256;
            pv16[idx] = f2bf(carry[j]);
            carry[j] = fmaf(dcy, carry[j], st[idx]);
        }
    }
}

// ---------------- Y from S_raw (setprio around MFMA clusters)
__global__ __launch_bounds__(256) void ssd_y2_k(const unsigned short* __restrict__ xc,
    const float* __restrict__ dtp, const float* __restrict__ acs_g,
    const unsigned short* __restrict__ sraw, const unsigned short* __restrict__ pv16,
    const float* __restrict__ Dp, unsigned short* __restrict__ Ybf)
{
    __shared__ unsigned short SXT[32 * SXS];
    int bid = blockIdx.x;
    int blk2 = (gridDim.x & 7) ? bid : ((bid & 7) * (gridDim.x >> 3) + (bid >> 3));
    int half = blk2 & 1;
    int blk = blk2 >> 1;
    int h = blk % NHH;
    int c = (blk / NHH) % NC;
    int b = blk / (NHH * NC);
    int tid = threadIdx.x;
    int w = tid >> 6, l = tid & 63;
    int lr = l & 15, lk = l >> 4;
    int pbase = half * 32;
    size_t rowbase = (size_t)b * SEQ + c * CHK;
    size_t dbase = (size_t)(b * NHH + h) * SEQ + c * CHK;
    for (int i = tid; i < 256 * 4; i += 256) {
        int z = i >> 2, p8 = (i & 3) * 8;
        float az0q = acs_g[dbase + (z & 192)];
        float e = az0q - acs_g[dbase + z];
        if (e > 60.f) e = 60.f;
        float sc = expf(e) * dtp[dbase + z];
        u16x8 v = *(const u16x8*)&xc[(rowbase + z) * CDIM + h * HDIM + pbase + p8];
#pragma unroll
        for (int e2 = 0; e2 < 8; ++e2)
            SXT[(p8 + e2) * SXS + z] = f2bf(bf2f(v[e2]) * sc);
    }
    float az0w = acs_g[dbase + w * 64];
    float esw[4][4];
#pragma unroll
    for (int mi = 0; mi < 4; ++mi)
#pragma unroll
        for (int r = 0; r < 4; ++r)
            esw[mi][r] = expf(acs_g[dbase + w * 64 + mi * 16 + lk * 4 + r] - az0w);
    __syncthreads();

    const unsigned short* tbase = sraw + (size_t)(b * NC + c) * 16 * 4096;
    const unsigned short* pvbase = pv16 + (size_t)blk * (HDIM * DSTATE);
    f32x4 acc[4][2] = {};
    for (int zt = 0; zt < w; ++zt) {
        const unsigned short* tp = tbase + (size_t)(w * 4 + zt) * 4096;
        f32x4 tmp[4][2] = {};
        __builtin_amdgcn_s_setprio(1);
#pragma unroll
        for (int kt = 0; kt < 2; ++kt) {
            bf16x8 av[4], bv[2];
#pragma unroll
            for (int mi = 0; mi < 4; ++mi)
                av[mi] = *(const bf16x8*)&tp[(mi * 16 + lr) * 64 + kt * 32 + lk * 8];
#pragma unroll
            for (int nj = 0; nj < 2; ++nj)
                bv[nj] = *(const bf16x8*)&SXT[(nj * 16 + lr) * SXS + zt * 64 + kt * 32 + lk * 8];
#pragma unroll
            for (int mi = 0; mi < 4; ++mi)
#pragma unroll
                for (int nj = 0; nj < 2; ++nj)
                    tmp[mi][nj] = __builtin_amdgcn_mfma_f32_16x16x32_bf16(av[mi], bv[nj], tmp[mi][nj], 0, 0, 0);
        }
        __builtin_amdgcn_s_setprio(0);
        float rho = expf(az0w - acs_g[dbase + zt * 64]);
#pragma unroll
        for (int mi = 0; mi < 4; ++mi)
#pragma unroll
            for (int r = 0; r < 4; ++r) {
                float es = esw[mi][r] * rho;
#pragma unroll
                for (int nj = 0; nj < 2; ++nj)
                    acc[mi][nj][r] += es * tmp[mi][nj][r];
            }
    }
    {
        const unsigned short* tp = tbase + (size_t)(w * 4 + w) * 4096;
        f32x4 tmp[4][2] = {};
        __builtin_amdgcn_s_setprio(1);
#pragma unroll
        for (int kt = 0; kt < 2; ++kt) {
            bf16x8 av[4], bv[2];
#pragma unroll
            for (int mi = 0; mi < 4; ++mi) {
                av[mi] = *(const bf16x8*)&tp[(mi * 16 + lr) * 64 + kt * 32 + lk * 8];
                int zb = kt * 32 + lk * 8;
                int sl = mi * 16 + lr;
#pragma unroll
                for (int e = 0; e < 8; ++e)
                    if (zb + e > sl) av[mi][e] = 0;
            }
#pragma unroll
            for (int nj = 0; nj < 2; ++nj)
                bv[nj] = *(const bf16x8*)&SXT[(nj * 16 + lr) * SXS + w * 64 + kt * 32 + lk * 8];
#pragma unroll
            for (int mi = 0; mi < 4; ++mi)
#pragma unroll
                for (int nj = 0; nj < 2; ++nj)
                    tmp[mi][nj] = __builtin_amdgcn_mfma_f32_16x16x32_bf16(av[mi], bv[nj], tmp[mi][nj], 0, 0, 0);
        }
        __builtin_amdgcn_s_setprio(0);
#pragma unroll
        for (int mi = 0; mi < 4; ++mi)
#pragma unroll
            for (int r = 0; r < 4; ++r) {
                float es = esw[mi][r];
#pragma unroll
                for (int nj = 0; nj < 2; ++nj)
                    acc[mi][nj][r] += es * tmp[mi][nj][r];
            }
    }
    {
        f32x4 tmp[4][2] = {};
        __builtin_amdgcn_s_setprio(1);
#pragma unroll
        for (int kt = 0; kt < 4; ++kt) {
            bf16x8 av[4], bv[2];
#pragma unroll
            for (int mi = 0; mi < 4; ++mi)
                av[mi] = *(const bf16x8*)&xc[(rowbase + w * 64 + mi * 16 + lr) * CDIM + DSSM + DSTATE + kt * 32 + lk * 8];
#pragma unroll
            for (int nj = 0; nj < 2; ++nj)
                bv[nj] = *(const bf16x8*)&pvbase[(pbase + nj * 16 + lr) * DSTATE + kt * 32 + lk * 8];
#pragma unroll
            for (int mi = 0; mi < 4; ++mi)
#pragma unroll
                for (int nj = 0; nj < 2; ++nj)
                    tmp[mi][nj] = __builtin_amdgcn_mfma_f32_16x16x32_bf16(av[mi], bv[nj], tmp[mi][nj], 0, 0, 0);
        }
        __builtin_amdgcn_s_setprio(0);
        float eoff = expf(az0w);
#pragma unroll
        for (int mi = 0; mi < 4; ++mi)
#pragma unroll
            for (int r = 0; r < 4; ++r) {
                float es = esw[mi][r] * eoff;
#pragma unroll
                for (int nj = 0; nj < 2; ++nj)
                    acc[mi][nj][r] += es * tmp[mi][nj][r];
            }
    }
    float dph = Dp[h];
#pragma unroll
    for (int mi = 0; mi < 4; ++mi) {
#pragma unroll
        for (int r = 0; r < 4; ++r) {
            int s = w * 64 + mi * 16 + lk * 4 + r;
#pragma unroll
            for (int nj = 0; nj < 2; ++nj) {
                int p = pbase + nj * 16 + lr;
                float xv = bf2f(xc[(rowbase + s) * CDIM + h * HDIM + p]);
                Ybf[(rowbase + s) * DSSM + h * HDIM + p] = f2bf(acc[mi][nj][r] + dph * xv);
            }
        }
    }
}

// ---------------- gated RMS norm
__global__ __launch_bounds__(256) void rmsnorm_k(const unsigned short* __restrict__ Ybf_in,
    const unsigned short* __restrict__ zbf, const float* __restrict__ nw,
    unsigned short* __restrict__ Ybf_out)
{
    __shared__ float red[8];
    int row = blockIdx.x;
    const unsigned short* y = Ybf_in + (size_t)row * DSSM;
    const unsigned short* z = zbf + (size_t)row * DSSM;
    float v[6];
    float ss = 0.f;
#pragma unroll
    for (int k = 0; k < 6; ++k) {
        int i = threadIdx.x + k * 256;
        float g = bf2f(y[i]) * siluf(bf2f(z[i]));
        v[k] = g;
        ss = fmaf(g, g, ss);
    }
#pragma unroll
    for (int o = 32; o > 0; o >>= 1) ss += __shfl_down(ss, o, 64);
    int wv = threadIdx.x >> 6, ln = threadIdx.x & 63;
    if (ln == 0) red[wv] = ss;
    __syncthreads();
    float tot = red[0] + red[1] + red[2] + red[3];
    float sc = rsqrtf(tot / (float)DSSM + 1e-12f);
    unsigned short* yo = Ybf_out + (size_t)row * DSSM;
#pragma unroll
    for (int k = 0; k < 6; ++k) {
        int i = threadIdx.x + k * 256;
        yo[i] = f2bf(v[k] * sc * nw[i]);
    }
}

// ---------------- MEGA3: out-proj GEMM (tri-buffered, swizzled) + timeout
__global__ __launch_bounds__(256) void gemm_out_timeout_k(
    const unsigned short* __restrict__ A, const unsigned short* __restrict__ B,
    const float* __restrict__ bias, float* __restrict__ C, int N, int K, int KT, int NT, int NWGG,
    const float* __restrict__ td, const float* __restrict__ tdt,
    const float* __restrict__ gw, const float* __restrict__ gb,
    const float* __restrict__ lnw, const float* __restrict__ lnb, float* __restrict__ out2)
{
    __shared__ __align__(16) unsigned char SMEMRAW[49152];
    unsigned short* SMEM = (unsigned short*)SMEMRAW;
    const int tid = threadIdx.x;
    int nwg = gridDim.x, bid = blockIdx.x;
    int wg = (nwg & 7) ? bid : ((bid & 7) * (nwg >> 3) + (bid >> 3));
    if (wg >= NWGG) {
        float* tm = (float*)SMEMRAW;
        __shared__ float red[8];
        int row = wg - NWGG;
        const float* tdr = td + (size_t)row * SEQ;
        const float* tdtr = tdt + (size_t)row * SEQ;
        int wv = tid >> 6, ln = tid & 63;
        float part = 0.f;
        for (int i = tid; i < SEQ; i += 256) part = fmaf(tdr[i], gw[i], part);
#pragma unroll
        for (int o = 32; o > 0; o >>= 1) part += __shfl_down(part, o, 64);
        if (ln == 0) red[wv] = part;
        __syncthreads();
        float dot = red[0] + red[1] + red[2] + red[3];
        float tg = 1.f / (1.f + expf(-(dot + gb[0])));
        __syncthreads();
        float sum = 0.f;
        for (int i = tid; i < SEQ; i += 256) {
            float x = tg * tdr[i] + (1.f - tg) * tdtr[i];
            tm[i] = x;
            sum += x;
        }
#pragma unroll
        for (int o = 32; o > 0; o >>= 1) sum += __shfl_down(sum, o, 64);
        if (ln == 0) red[wv] = sum;
        __syncthreads();
        float mu = (red[0] + red[1] + red[2] + red[3]) / (float)SEQ;
        __syncthreads();
        float s2 = 0.f;
        for (int i = tid; i < SEQ; i += 256) { float d = tm[i] - mu; s2 = fmaf(d, d, s2); }
#pragma unroll
        for (int o = 32; o > 0; o >>= 1) s2 += __shfl_down(s2, o, 64);
        if (ln == 0) red[wv] = s2;
        __syncthreads();
        float var = (red[0] + red[1] + red[2] + red[3]) / (float)SEQ;
        float inv = rsqrtf(var + 1e-12f);
        for (int i = tid; i < SEQ; i += 256)
            out2[(size_t)row * SEQ + i] = (tm[i] - mu) * inv * lnw[i] + lnb[i];
        return;
    }
    const int w = tid >> 6, l = tid & 63;
    const int wr = w >> 1, wc = w & 1;
    const int lr = l & 15, lk = l >> 4;
    const int lkx = lk ^ ((lr >> 1) & 3);
    const int m0 = (wg / NT) * 128, n0 = (wg % NT) * 128;
    f32x4 acc[4][4] = {};
    const int i16 = w * 64 + l;
    const int row0 = i16 >> 2, sl = i16 & 3;
    const int slx = sl ^ ((row0 >> 1) & 3);
    const size_t ga0 = (size_t)(m0 + row0) * K + slx * 8;
    const size_t ga1 = (size_t)(m0 + row0 + 64) * K + slx * 8;
    const size_t gb0 = (size_t)(n0 + row0) * K + slx * 8;
    const size_t gb1 = (size_t)(n0 + row0 + 64) * K + slx * 8;
    const int lo0 = (w * 64) * 8;
    const int lo1 = (256 + w * 64) * 8;

#define STAGE3(bb, kt) { int ko = (kt) * 32; int bs = (bb) * 8192;           \
      gload_lds16(A + ga0 + ko, &SMEM[bs + lo0]);                            \
      gload_lds16(A + ga1 + ko, &SMEM[bs + lo1]);                            \
      gload_lds16(B + gb0 + ko, &SMEM[bs + 4096 + lo0]);                     \
      gload_lds16(B + gb1 + ko, &SMEM[bs + 4096 + lo1]); }

    STAGE3(0, 0);
    STAGE3(1, 1);
    for (int kt = 0; kt < KT; ++kt) {
        if (kt + 1 < KT) {
            asm volatile("s_waitcnt vmcnt(4)" ::: "memory");
        } else {
            asm volatile("s_waitcnt vmcnt(0)" ::: "memory");
        }
        __builtin_amdgcn_s_barrier();
        if (kt + 2 < KT) STAGE3((kt + 2) % 3, kt + 2);
        int bs = (kt % 3) * 8192;
        bf16x8 af[4], bg[4];
#pragma unroll
        for (int mi = 0; mi < 4; ++mi)
            af[mi] = *(const bf16x8*)&SMEM[bs + (wr * 64 + mi * 16 + lr) * 32 + lkx * 8];
#pragma unroll
        for (int nj = 0; nj < 4; ++nj)
            bg[nj] = *(const bf16x8*)&SMEM[bs + 4096 + (wc * 64 + nj * 16 + lr) * 32 + lkx * 8];
#pragma unroll
        for (int mi = 0; mi < 4; ++mi)
#pragma unroll
            for (int nj = 0; nj < 4; ++nj)
                acc[mi][nj] = __builtin_amdgcn_mfma_f32_16x16x32_bf16(af[mi], bg[nj], acc[mi][nj], 0, 0, 0);
    }
#undef STAGE3
#pragma unroll
    for (int nj = 0; nj < 4; ++nj) {
        int col = n0 + wc * 64 + nj * 16 + lr;
        float bz = bias[col];
#pragma unroll
        for (int mi = 0; mi < 4; ++mi) {
#pragma unroll
            for (int r = 0; r < 4; ++r) {
                int m = m0 + wr * 64 + mi * 16 + lk * 4 + r;
                C[(size_t)m * N + col] = acc[mi][nj][r] + bz;
            }
        }
    }
}

extern "C" void kernel_launch(void* const* d_in, const int* in_sizes, int n_in,
                              void* d_out, int out_size, void* d_ws, size_t ws_size,
                              hipStream_t stream)
{
    const float* u      = (const float*)d_in[0];
    const float* td     = (const float*)d_in[1];
    const float* W_in   = (const float*)d_in[2];
    const float* b_in   = (const float*)d_in[3];
    const float* conv_w = (const float*)d_in[4];
    const float* conv_b = (const float*)d_in[5];
    const float* t1w    = (const float*)d_in[6];
    const float* t1b    = (const float*)d_in[7];
    const float* t2w    = (const float*)d_in[8];
    const float* t2b    = (const float*)d_in[9];
    const float* m1w    = (const float*)d_in[10];
    const float* m1b    = (const float*)d_in[11];
    const float* m2w    = (const float*)d_in[12];
    const float* m2b    = (const float*)d_in[13];
    const float* gw     = (const float*)d_in[14];
    const float* gb     = (const float*)d_in[15];
    const float* lnw    = (const float*)d_in[16];
    const float* lnb    = (const float*)d_in[17];
    const float* A_log  = (const float*)d_in[18];
    const float* dt_bias= (const float*)d_in[19];
    const float* Dpv    = (const float*)d_in[20];
    const float* nw     = (const float*)d_in[21];
    const float* W_out  = (const float*)d_in[22];
    const float* b_out  = (const float*)d_in[23];
    float* out  = (float*)d_out;
    float* out2 = out + (size_t)MR * DMODEL;

    float* ws = (float*)d_ws;
    size_t o = 0;
    float* zbuf  = ws + o; o += (size_t)MR * DSSM;
    float* r1    = ws + o; o += (size_t)MR * DSSM;
    float* xcv   = ws + o; o += (size_t)MR * CDIM / 2;
    float* partb = ws + o; o += (size_t)KSPLIT * 48 * SEQ;
    float* hid   = ws + o; o += (size_t)BB * NHH * SEQ;
    float* tss   = ws + o; o += (size_t)BB * NHH * SEQ;
    float* tdt   = ws + o; o += (size_t)BB * NHH * SEQ;
    float* dtp   = ws + o; o += (size_t)MR * NHH;
    float* acs_g = ws + o; o += (size_t)MR * NHH;
    float* pvb   = ws + o; o += (size_t)BB * NC * NHH * HDIM * DSTATE;
    unsigned short* sraw = (unsigned short*)(ws + o); o += (size_t)BB * NC * 16 * 4096 / 2;
    unsigned short* r1b = (unsigned short*)r1;
    float* stb = r1;
    unsigned short* ybf16 = (unsigned short*)r1;
    unsigned short* xcv_bf = (unsigned short*)xcv;
    unsigned short* u_bf  = (unsigned short*)pvb;
    unsigned short* Wi_bf = (unsigned short*)(pvb + 3145728);
    unsigned short* pv16  = (unsigned short*)pvb;
    unsigned short* zbf   = (unsigned short*)zbuf;
    unsigned short* Y_bf  = (unsigned short*)xcv;
    unsigned short* Wo_bf = (unsigned short*)(zbuf + 6291456);

    dim3 blk(256);
    const int NWG1 = (XSTR / 128) * (MR / 128);          // 960
    const int NWGD = NWG1 + (DSSM / 128) * (MR / 128);   // 1728
    const int NWGSK = (SEQ / 128) * KSPLIT;              // 1024
    const int NWGC = 448 * (MR / CT) / 256;              // 896
    const int NB0 = MR * DMODEL / 1024;                  // 6144
    const int NB1 = 3456 * DMODEL / 1024;                // 2592
    const int NB2 = DMODEL * DSSM / 1024;                // 1152

    cvt3_k<<<dim3(NB0 + NB1 + NB2), blk, 0, stream>>>(
        u, u_bf, NB0, MR * DMODEL,
        W_in, Wi_bf, NB1, DPROJ * DMODEL,
        W_out, Wo_bf, NB2, DMODEL * DSSM);
    // --- MEGA1: dual in-proj GEMM (LDS tri-buffered) + skinny1 ---
    gemm_dual_skinny<<<dim3(NWGD + NWGSK), blk, 0, stream>>>(
        u_bf,
        Wi_bf + (size_t)DSSM * DMODEL, b_in + DSSM, r1b, XSTR, XSTR / 128, DPROJ - DSSM, NWG1,
        Wi_bf, b_in, zbf, DSSM, DSSM / 128, DSSM,
        DMODEL, DMODEL / 32, NWGD,
        td, m1w, partb, SEQ, SEQ);
    reduce_part_k<<<dim3((48 * SEQ + 255) / 256), blk, 0, stream>>>(partb, m1b, hid, SEQ, 1);
    // --- MEGA2: conv + skinny2 (hid @ m2w) ---
    conv_skinny2_k<<<dim3(NWGC + NWGSK), blk, 0, stream>>>(
        r1b, conv_w, conv_b, xcv_bf, hid, m2w, partb, SEQ, SEQ, NWGC);
    reduce_part_k<<<dim3((48 * SEQ + 255) / 256), blk, 0, stream>>>(partb, m2b, tss, SEQ, 0);
    time_conv_k<<<dim3(BB * NHH * 4), blk, 0, stream>>>(tss, td, t1w, t1b, t2w, t2b, tdt);
    dtsp_cum_k<<<dim3(BB * NHH * NC), blk, 0, stream>>>(r1b, tdt, dt_bias, A_log, dtp, acs_g);
    ssd_states_sraw_k<<<dim3(BB * NC * NHH + BB * NC * 10), blk, 0, stream>>>(xcv_bf, dtp, acs_g, stb, sraw);
    ssd_scan_k<<<dim3(BB * NHH * 8), blk, 0, stream>>>(stb, acs_g, pv16);
    ssd_y2_k<<<dim3(BB * NC * NHH * 2), blk, 0, stream>>>(xcv_bf, dtp, acs_g, sraw, pv16, Dpv, ybf16);
    rmsnorm_k<<<dim3(MR), blk, 0, stream>>>(ybf16, zbf, nw, Y_bf);
    gemm_out_timeout_k<<<dim3((DMODEL / 128) * (MR / 128) + BB * NHH), blk, 0, stream>>>(
        Y_bf, Wo_bf, b_out, out, DMODEL, DSSM, DSSM / 32, DMODEL / 128, (DMODEL / 128) * (MR / 128),
        td, tdt, gw, gb, lnw, lnb, out2);
}